// Round 6
// baseline (11163.313 us; speedup 1.0000x reference)
//
#include <hip/hip_runtime.h>

// ---------------------------------------------------------------------------
// 2-layer GRU (B=64,T=1024,D=256,H=512) + dense head, persistent-RNN style.
// v7: counter-barrier + epoch-tagged data, spill-proof nested phases.
//   - Detection: per-layer arrive counters (4 lines each, atomicAdd), polled
//     with ONE 4B load/lane + 2 shfl_xor. No 64-line flag gather.
//   - No producer store-drain: arrival issued after stores ISSUED; h and y
//     are epoch-tagged u32 (tag<<16|f16); consumers validate + retry (rare).
//   - All exchange loads are self-contained asm blocks (issue + vmcnt(0)
//     inside), phase-split so no tag array is live across another block
//     (v6's spill-to-scratch killer).
//   - Wait condition (both layers, iter s): cntL0 >= 32s AND cntL1 >= 32(s-1).
//   - y 2-slot tagged, hosted in out-head + c0 region; c0 written in a
//     counter-gated epilogue. All spins watchdog'd + dead-latch: hang-proof.
// ---------------------------------------------------------------------------

#define T_STEPS 1024
#define NWG_L0  32
#define NWG_TOT 64

typedef _Float16 f16x8 __attribute__((ext_vector_type(8)));
typedef float    f32x4 __attribute__((ext_vector_type(4)));

// ws layout (bytes)
#define H0T_OFF 0u          // 2 slots x [64][512] u32 = 262144
#define H1T_OFF 262144u     // 2 slots x [64][512] u32 = 262144
#define CNT_OFF 524288u     // 8 lines x 128B (lines 0-3: L0, 4-7: L1)
#define WS_NEED 525312u

#define BUD_SPIN (1ull << 19)   // ~220us, then dead-latch
#define BUD_EPI  (1ull << 22)

__device__ __forceinline__ float sigm_f(float x) { return 1.0f / (1.0f + __expf(-x)); }
__device__ __forceinline__ float tanh_f(float x) { return 2.0f / (1.0f + __expf(-2.0f * x)) - 1.0f; }

__device__ __forceinline__ f32x4 mfma16(f16x8 a, f16x8 b, f32x4 c) {
    return __builtin_amdgcn_mfma_f32_16x16x32_f16(a, b, c, 0, 0, 0);
}

__device__ __forceinline__ f16x8 pack8(const float* __restrict__ src, int stride) {
    f16x8 r;
#pragma unroll
    for (int j = 0; j < 8; ++j) r[j] = (_Float16)src[j * stride];
    return r;
}

// ---- self-contained tagged-batch loads (issue + vmcnt(0) inside) ----
// 16 dwordx4 = 8 fragments (kt group of 8) from one base.
#define LDB16(W, B) \
  asm volatile( \
    "global_load_dwordx4 %0, %16, off sc1\n\t" \
    "global_load_dwordx4 %1, %16, off offset:16 sc1\n\t" \
    "global_load_dwordx4 %2, %16, off offset:128 sc1\n\t" \
    "global_load_dwordx4 %3, %16, off offset:144 sc1\n\t" \
    "global_load_dwordx4 %4, %16, off offset:256 sc1\n\t" \
    "global_load_dwordx4 %5, %16, off offset:272 sc1\n\t" \
    "global_load_dwordx4 %6, %16, off offset:384 sc1\n\t" \
    "global_load_dwordx4 %7, %16, off offset:400 sc1\n\t" \
    "global_load_dwordx4 %8, %16, off offset:512 sc1\n\t" \
    "global_load_dwordx4 %9, %16, off offset:528 sc1\n\t" \
    "global_load_dwordx4 %10, %16, off offset:640 sc1\n\t" \
    "global_load_dwordx4 %11, %16, off offset:656 sc1\n\t" \
    "global_load_dwordx4 %12, %16, off offset:768 sc1\n\t" \
    "global_load_dwordx4 %13, %16, off offset:784 sc1\n\t" \
    "global_load_dwordx4 %14, %16, off offset:896 sc1\n\t" \
    "global_load_dwordx4 %15, %16, off offset:912 sc1\n\t" \
    "s_waitcnt vmcnt(0)" \
    : "=&v"((W)[0]), "=&v"((W)[1]), "=&v"((W)[2]), "=&v"((W)[3]), \
      "=&v"((W)[4]), "=&v"((W)[5]), "=&v"((W)[6]), "=&v"((W)[7]), \
      "=&v"((W)[8]), "=&v"((W)[9]), "=&v"((W)[10]), "=&v"((W)[11]), \
      "=&v"((W)[12]), "=&v"((W)[13]), "=&v"((W)[14]), "=&v"((W)[15]) \
    : "v"(B) \
    : "memory")

// 32 dwordx4: 8 h-frags from HB (%32) + 8 y-frags from YB (%33)
#define LDHY32(W, HB, YB) \
  asm volatile( \
    "global_load_dwordx4 %0, %32, off sc1\n\t" \
    "global_load_dwordx4 %1, %32, off offset:16 sc1\n\t" \
    "global_load_dwordx4 %2, %32, off offset:128 sc1\n\t" \
    "global_load_dwordx4 %3, %32, off offset:144 sc1\n\t" \
    "global_load_dwordx4 %4, %32, off offset:256 sc1\n\t" \
    "global_load_dwordx4 %5, %32, off offset:272 sc1\n\t" \
    "global_load_dwordx4 %6, %32, off offset:384 sc1\n\t" \
    "global_load_dwordx4 %7, %32, off offset:400 sc1\n\t" \
    "global_load_dwordx4 %8, %32, off offset:512 sc1\n\t" \
    "global_load_dwordx4 %9, %32, off offset:528 sc1\n\t" \
    "global_load_dwordx4 %10, %32, off offset:640 sc1\n\t" \
    "global_load_dwordx4 %11, %32, off offset:656 sc1\n\t" \
    "global_load_dwordx4 %12, %32, off offset:768 sc1\n\t" \
    "global_load_dwordx4 %13, %32, off offset:784 sc1\n\t" \
    "global_load_dwordx4 %14, %32, off offset:896 sc1\n\t" \
    "global_load_dwordx4 %15, %32, off offset:912 sc1\n\t" \
    "global_load_dwordx4 %16, %33, off sc1\n\t" \
    "global_load_dwordx4 %17, %33, off offset:16 sc1\n\t" \
    "global_load_dwordx4 %18, %33, off offset:128 sc1\n\t" \
    "global_load_dwordx4 %19, %33, off offset:144 sc1\n\t" \
    "global_load_dwordx4 %20, %33, off offset:256 sc1\n\t" \
    "global_load_dwordx4 %21, %33, off offset:272 sc1\n\t" \
    "global_load_dwordx4 %22, %33, off offset:384 sc1\n\t" \
    "global_load_dwordx4 %23, %33, off offset:400 sc1\n\t" \
    "global_load_dwordx4 %24, %33, off offset:512 sc1\n\t" \
    "global_load_dwordx4 %25, %33, off offset:528 sc1\n\t" \
    "global_load_dwordx4 %26, %33, off offset:640 sc1\n\t" \
    "global_load_dwordx4 %27, %33, off offset:656 sc1\n\t" \
    "global_load_dwordx4 %28, %33, off offset:768 sc1\n\t" \
    "global_load_dwordx4 %29, %33, off offset:784 sc1\n\t" \
    "global_load_dwordx4 %30, %33, off offset:896 sc1\n\t" \
    "global_load_dwordx4 %31, %33, off offset:912 sc1\n\t" \
    "s_waitcnt vmcnt(0)" \
    : "=&v"((W)[0]), "=&v"((W)[1]), "=&v"((W)[2]), "=&v"((W)[3]), \
      "=&v"((W)[4]), "=&v"((W)[5]), "=&v"((W)[6]), "=&v"((W)[7]), \
      "=&v"((W)[8]), "=&v"((W)[9]), "=&v"((W)[10]), "=&v"((W)[11]), \
      "=&v"((W)[12]), "=&v"((W)[13]), "=&v"((W)[14]), "=&v"((W)[15]), \
      "=&v"((W)[16]), "=&v"((W)[17]), "=&v"((W)[18]), "=&v"((W)[19]), \
      "=&v"((W)[20]), "=&v"((W)[21]), "=&v"((W)[22]), "=&v"((W)[23]), \
      "=&v"((W)[24]), "=&v"((W)[25]), "=&v"((W)[26]), "=&v"((W)[27]), \
      "=&v"((W)[28]), "=&v"((W)[29]), "=&v"((W)[30]), "=&v"((W)[31]) \
    : "v"(HB), "v"(YB) \
    : "memory")

__device__ __forceinline__ void st_u1_sc1(unsigned* p, unsigned v) {
    asm volatile("global_store_dword %0, %1, off sc1" :: "v"(p), "v"(v) : "memory");
}

// counter spin: lane loads line (lane&7); sum groups of 4 via shfl_xor;
// lanes with (lane&7)<4 hold cntL0 sum, others cntL1 sum. tgt is per-lane.
__device__ __forceinline__ void spin_cnt(const unsigned* pl, int tgt, bool* dead,
                                         unsigned long long bud) {
    if (*dead) return;
    unsigned long long t0 = clock64();
    for (;;) {
        unsigned v;
        asm volatile("global_load_dword %0, %1, off sc1\n\ts_waitcnt vmcnt(0)"
                     : "=v"(v) : "v"(pl) : "memory");
        int sv = (int)v;
        sv += __shfl_xor(sv, 1);
        sv += __shfl_xor(sv, 2);
        if (__all(sv >= tgt)) return;
        if (clock64() - t0 > bud) { *dead = true; return; }
    }
}

__device__ __forceinline__ unsigned vb16(const uint4* w, unsigned etag) {
    unsigned a = 0;
#pragma unroll
    for (int i = 0; i < 16; ++i)
        a |= (w[i].x ^ etag) | (w[i].y ^ etag) | (w[i].z ^ etag) | (w[i].w ^ etag);
    return a >> 16;
}
__device__ __forceinline__ f16x8 packfrag(uint4 lo, uint4 hi) {
    uint4 r;
    r.x = (lo.x & 0xFFFFu) | (lo.y << 16);
    r.y = (lo.z & 0xFFFFu) | (lo.w << 16);
    r.z = (hi.x & 0xFFFFu) | (hi.y << 16);
    r.w = (hi.z & 0xFFFFu) | (hi.w << 16);
    return __builtin_bit_cast(f16x8, r);
}

#define BFRAG(g, kt) __builtin_bit_cast(f16x8, ldsB[((g) * 16 + (kt)) * 64 + lane])
#define WFRAG(g, kt) __builtin_bit_cast(f16x8, ldsWi[((g) * 16 + (kt)) * 64 + lane])

__global__ __launch_bounds__(256, 1) void gru_scan(
    const float* __restrict__ x,     // [64,1024,256]
    const float* __restrict__ Wi0, const float* __restrict__ bi0,
    const float* __restrict__ Wh0, const float* __restrict__ bhn0,
    const float* __restrict__ Wi1, const float* __restrict__ bi1,
    const float* __restrict__ Wh1, const float* __restrict__ bhn1,
    float* __restrict__ c0_out,      // [64,512] (== y slot 1 region)
    float* __restrict__ c1_out,      // [64,512]
    unsigned* __restrict__ y0u,      // y slot 0 tagged (out head region)
    unsigned* __restrict__ y1u,      // y slot 1 tagged (c0 region)
    unsigned char* __restrict__ ws)
{
    __shared__ uint4 ldsB[48 * 64];   // W_h fragments (48 KB)
    __shared__ uint4 ldsWi[48 * 64];  // W_i fragments (48 KB; L0 uses kt<8)

    const int tid  = threadIdx.x;
    const int lane = tid & 63;
    const int wave = tid >> 6;
    const int quad = lane >> 4;
    const int l16  = lane & 15;
    const int wg   = blockIdx.x;
    const bool isL1 = (wg >= NWG_L0);
    const int rank = isL1 ? (wg - NWG_L0) : wg;
    const int cslice = rank * 16;

    unsigned* cbase = (unsigned*)(ws + CNT_OFF);
    const unsigned* cline = cbase + (lane & 7) * 32;                // poll line
    unsigned* myCnt = cbase + ((isL1 ? 4 : 0) + (rank & 3)) * 32;   // arrive line

    const float* Wh = isL1 ? Wh1 : Wh0;
    const float* Wi = isL1 ? Wi1 : Wi0;

    // ---- stage W_h / W_i fragments into LDS ----
    for (int f = wave * 12; f < wave * 12 + 12; ++f) {
        int nt = f >> 4, kt = f & 15;
        const float* src = Wh + (kt * 32 + quad * 8) * 1536 + nt * 512 + cslice + l16;
        ldsB[f * 64 + lane] = __builtin_bit_cast(uint4, pack8(src, 1536));
        if (isL1 || kt < 8) {
            const float* si = Wi + (kt * 32 + quad * 8) * 1536 + nt * 512 + cslice + l16;
            ldsWi[f * 64 + lane] = __builtin_bit_cast(uint4, pack8(si, 1536));
        }
    }

    const float* bi = isL1 ? bi1 : bi0;
    const float* bh = isL1 ? bhn1 : bhn0;
    const float bi_r = bi[cslice + l16];
    const float bi_z = bi[512 + cslice + l16];
    const float bi_n = bi[1024 + cslice + l16];
    const float bhn  = bh[cslice + l16];

    __syncthreads();

    float hstate[4] = {0.f, 0.f, 0.f, 0.f};
    const int rowA = wave * 16 + l16;
    const int rowC = wave * 16 + quad * 4;
    const int cu   = cslice + l16;
    const f32x4 z4 = {0.f, 0.f, 0.f, 0.f};
    bool dead = false;
    const bool loLane = (lane & 7) < 4;

    if (!isL1) {
        // ================================ L0 ================================
        unsigned* h0t = (unsigned*)(ws + H0T_OFF);
        float c0st[4] = {0.f, 0.f, 0.f, 0.f};

        // prologue: x(0) plain loads
        f32x4 xr[16];
        {
            const float* px = x + (size_t)rowA * 262144 + quad * 8;
#pragma unroll
            for (int kt = 0; kt < 8; ++kt) {
                xr[2 * kt]     = *(const f32x4*)(px + kt * 32);
                xr[2 * kt + 1] = *(const f32x4*)(px + kt * 32 + 4);
            }
        }

        for (int s = 0; s < T_STEPS; ++s) {
            // wait: cntL0 >= 32s AND cntL1 >= 32(s-1)
            if (s > 0)
                spin_cnt(cline, loLane ? 32 * s : 32 * s - 32, &dead, BUD_SPIN);

            // convert x(s) -> f16 A-frags (compiler waits xr loads here)
            f16x8 axf[8];
#pragma unroll
            for (int kt = 0; kt < 8; ++kt) {
                f32x4 x0 = xr[2 * kt], x1 = xr[2 * kt + 1];
                f16x8 a;
                a[0] = (_Float16)x0[0]; a[1] = (_Float16)x0[1];
                a[2] = (_Float16)x0[2]; a[3] = (_Float16)x0[3];
                a[4] = (_Float16)x1[0]; a[5] = (_Float16)x1[1];
                a[6] = (_Float16)x1[2]; a[7] = (_Float16)x1[3];
                axf[kt] = a;
            }

            const unsigned etag = (unsigned)s << 16;
            const unsigned* hb = h0t + (unsigned)(s & 1) * 32768u + rowA * 512 + quad * 8;

            f32x4 ax0 = z4, ax1 = z4, ax2 = z4, ah0 = z4, ah1 = z4, ah2 = z4;

            // phase A: h kt 0-7
            {
                uint4 wa[16];
                LDB16(wa, hb);
                unsigned bad = vb16(wa, etag);
                if (__any((int)(bad != 0u)) && !dead) {
                    unsigned long long t0 = clock64();
                    while (__any((int)(bad != 0u))) {
                        LDB16(wa, hb);
                        bad = vb16(wa, etag);
                        if (clock64() - t0 > BUD_SPIN) { dead = true; break; }
                    }
                }
#pragma unroll
                for (int kt = 0; kt < 8; ++kt) {
                    f16x8 a = packfrag(wa[2 * kt], wa[2 * kt + 1]);
                    ah0 = mfma16(a, BFRAG(0, kt), ah0);
                    ah1 = mfma16(a, BFRAG(1, kt), ah1);
                    ah2 = mfma16(a, BFRAG(2, kt), ah2);
                    ax0 = mfma16(axf[kt], WFRAG(0, kt), ax0);
                    ax1 = mfma16(axf[kt], WFRAG(1, kt), ax1);
                    ax2 = mfma16(axf[kt], WFRAG(2, kt), ax2);
                }
            }
            // phase B: h kt 8-15
            {
                uint4 wa[16];
                LDB16(wa, hb + 256);
                unsigned bad = vb16(wa, etag);
                if (__any((int)(bad != 0u)) && !dead) {
                    unsigned long long t0 = clock64();
                    while (__any((int)(bad != 0u))) {
                        LDB16(wa, hb + 256);
                        bad = vb16(wa, etag);
                        if (clock64() - t0 > BUD_SPIN) { dead = true; break; }
                    }
                }
#pragma unroll
                for (int kt = 8; kt < 16; ++kt) {
                    f16x8 a = packfrag(wa[2 * (kt - 8)], wa[2 * (kt - 8) + 1]);
                    ah0 = mfma16(a, BFRAG(0, kt), ah0);
                    ah1 = mfma16(a, BFRAG(1, kt), ah1);
                    ah2 = mfma16(a, BFRAG(2, kt), ah2);
                }
            }

            float hnv[4], ytv[4];
#pragma unroll
            for (int i = 0; i < 4; ++i) {
                float r  = sigm_f(ax0[i] + bi_r + ah0[i]);
                float zz = sigm_f(ax1[i] + bi_z + ah1[i]);
                float n  = tanh_f(ax2[i] + bi_n + r * (ah2[i] + bhn));
                float hnew = (1.0f - zz) * n + zz * hstate[i];
                hstate[i] = hnew; hnv[i] = hnew; ytv[i] = tanh_f(hnew);
            }

            // stores: h0(s+1) + y(s+1), both tagged (no drain before arrival)
            unsigned* hw = h0t + (unsigned)((s + 1) & 1) * 32768u;
            unsigned* yw = ((s + 1) & 1) ? y1u : y0u;
            const unsigned wtag = (unsigned)(s + 1) << 16;
#pragma unroll
            for (int i = 0; i < 4; ++i) {
                unsigned hb16 = (unsigned)__builtin_bit_cast(unsigned short, (_Float16)hnv[i]);
                unsigned yb16 = (unsigned)__builtin_bit_cast(unsigned short, (_Float16)ytv[i]);
                st_u1_sc1(hw + (rowC + i) * 512 + cu, wtag | hb16);
                st_u1_sc1(yw + (rowC + i) * 512 + cu, wtag | yb16);
            }
            if (s == T_STEPS - 1) {
#pragma unroll
                for (int i = 0; i < 4; ++i) c0st[i] = hnv[i];
            }

            // prefetch x(s+1) (plain; compiler waits at next conversion)
            if (s + 1 < T_STEPS) {
                const float* px = x + (size_t)rowA * 262144 + (size_t)(s + 1) * 256 + quad * 8;
#pragma unroll
                for (int kt = 0; kt < 8; ++kt) {
                    xr[2 * kt]     = *(const f32x4*)(px + kt * 32);
                    xr[2 * kt + 1] = *(const f32x4*)(px + kt * 32 + 4);
                }
            }

            __syncthreads();
            if (tid == 0) atomicAdd(myCnt, 1u);
        }

        // epilogue: c0 region (= y slot 1) free once L1 finished iter 1023
        spin_cnt(cline, loLane ? (-2147483647 - 1) : 32 * 1023, &dead, BUD_EPI);
#pragma unroll
        for (int i = 0; i < 4; ++i)
            c0_out[(rowC + i) * 512 + cu] = c0st[i];

    } else {
        // ================================ L1 ================================
        unsigned* h1t = (unsigned*)(ws + H1T_OFF);

        for (int s = 1; s <= T_STEPS; ++s) {
            spin_cnt(cline, loLane ? 32 * s : 32 * s - 32, &dead, BUD_SPIN);

            const unsigned etagH = (unsigned)(s - 1) << 16;
            const unsigned etagY = (unsigned)s << 16;
            const unsigned* hb = h1t + (unsigned)((s - 1) & 1) * 32768u + rowA * 512 + quad * 8;
            const unsigned* yb = ((s & 1) ? y1u : y0u) + rowA * 512 + quad * 8;

            f32x4 ax0 = z4, ax1 = z4, ax2 = z4, ah0 = z4, ah1 = z4, ah2 = z4;

            // phase A: h kt 0-7 + y kt 0-7 in one block
            {
                uint4 wa[32];
                LDHY32(wa, hb, yb);
                unsigned bad = vb16(wa, etagH) | vb16(wa + 16, etagY);
                if (__any((int)(bad != 0u)) && !dead) {
                    unsigned long long t0 = clock64();
                    while (__any((int)(bad != 0u))) {
                        LDHY32(wa, hb, yb);
                        bad = vb16(wa, etagH) | vb16(wa + 16, etagY);
                        if (clock64() - t0 > BUD_SPIN) { dead = true; break; }
                    }
                }
#pragma unroll
                for (int kt = 0; kt < 8; ++kt) {
                    f16x8 ah = packfrag(wa[2 * kt], wa[2 * kt + 1]);
                    f16x8 ay = packfrag(wa[16 + 2 * kt], wa[16 + 2 * kt + 1]);
                    ah0 = mfma16(ah, BFRAG(0, kt), ah0);
                    ah1 = mfma16(ah, BFRAG(1, kt), ah1);
                    ah2 = mfma16(ah, BFRAG(2, kt), ah2);
                    ax0 = mfma16(ay, WFRAG(0, kt), ax0);
                    ax1 = mfma16(ay, WFRAG(1, kt), ax1);
                    ax2 = mfma16(ay, WFRAG(2, kt), ax2);
                }
            }
            // phase B: kt 8-15
            {
                uint4 wa[32];
                LDHY32(wa, hb + 256, yb + 256);
                unsigned bad = vb16(wa, etagH) | vb16(wa + 16, etagY);
                if (__any((int)(bad != 0u)) && !dead) {
                    unsigned long long t0 = clock64();
                    while (__any((int)(bad != 0u))) {
                        LDHY32(wa, hb + 256, yb + 256);
                        bad = vb16(wa, etagH) | vb16(wa + 16, etagY);
                        if (clock64() - t0 > BUD_SPIN) { dead = true; break; }
                    }
                }
#pragma unroll
                for (int kt = 8; kt < 16; ++kt) {
                    f16x8 ah = packfrag(wa[2 * (kt - 8)], wa[2 * (kt - 8) + 1]);
                    f16x8 ay = packfrag(wa[16 + 2 * (kt - 8)], wa[16 + 2 * (kt - 8) + 1]);
                    ah0 = mfma16(ah, BFRAG(0, kt), ah0);
                    ah1 = mfma16(ah, BFRAG(1, kt), ah1);
                    ah2 = mfma16(ah, BFRAG(2, kt), ah2);
                    ax0 = mfma16(ay, WFRAG(0, kt), ax0);
                    ax1 = mfma16(ay, WFRAG(1, kt), ax1);
                    ax2 = mfma16(ay, WFRAG(2, kt), ax2);
                }
            }

            float hnv[4];
#pragma unroll
            for (int i = 0; i < 4; ++i) {
                float r  = sigm_f(ax0[i] + bi_r + ah0[i]);
                float zz = sigm_f(ax1[i] + bi_z + ah1[i]);
                float n  = tanh_f(ax2[i] + bi_n + r * (ah2[i] + bhn));
                float hnew = (1.0f - zz) * n + zz * hstate[i];
                hstate[i] = hnew; hnv[i] = hnew;
            }

            unsigned* hw = h1t + (unsigned)(s & 1) * 32768u;
            const unsigned wtag = (unsigned)s << 16;
#pragma unroll
            for (int i = 0; i < 4; ++i) {
                unsigned hb16 = (unsigned)__builtin_bit_cast(unsigned short, (_Float16)hnv[i]);
                st_u1_sc1(hw + (rowC + i) * 512 + cu, wtag | hb16);
                if (s == T_STEPS) c1_out[(rowC + i) * 512 + cu] = hnv[i];
            }

            if (s < T_STEPS) {
                __syncthreads();
                if (tid == 0) atomicAdd(myCnt, 1u);
            }
        }
    }
}

// out = tanh(tanh(c1) @ W_out + b_out) : [64,512] @ [512,512], fp32
__global__ __launch_bounds__(256) void dense_out(
    const float* __restrict__ c1, const float* __restrict__ Wout,
    const float* __restrict__ bout, float* __restrict__ out)
{
    __shared__ float a[512];
    const int b = blockIdx.x, tid = threadIdx.x;
    a[tid]       = tanh_f(c1[b * 512 + tid]);
    a[tid + 256] = tanh_f(c1[b * 512 + tid + 256]);
    __syncthreads();
    float acc0 = 0.f, acc1 = 0.f;
#pragma unroll 4
    for (int k = 0; k < 512; ++k) {
        const float av = a[k];
        acc0 += av * Wout[k * 512 + tid];
        acc1 += av * Wout[k * 512 + tid + 256];
    }
    out[b * 512 + tid]       = tanh_f(acc0 + bout[tid]);
    out[b * 512 + tid + 256] = tanh_f(acc1 + bout[tid + 256]);
}

extern "C" void kernel_launch(void* const* d_in, const int* in_sizes, int n_in,
                              void* d_out, int out_size, void* d_ws, size_t ws_size,
                              hipStream_t stream)
{
    const float* x    = (const float*)d_in[0];
    const float* Wi0  = (const float*)d_in[1];
    const float* bi0  = (const float*)d_in[2];
    const float* Wh0  = (const float*)d_in[3];
    const float* bhn0 = (const float*)d_in[4];
    const float* Wi1  = (const float*)d_in[5];
    const float* bi1  = (const float*)d_in[6];
    const float* Wh1  = (const float*)d_in[7];
    const float* bhn1 = (const float*)d_in[8];
    const float* Wout = (const float*)d_in[9];
    const float* bout = (const float*)d_in[10];
    float* out = (float*)d_out;
    unsigned char* ws = (unsigned char*)d_ws;

    float* c0 = out + 32768;
    float* c1 = out + 65536;
    unsigned* y0u = (unsigned*)out;   // y slot 0: out head, [64][512] u32
    unsigned* y1u = (unsigned*)c0;    // y slot 1: c0 region, [64][512] u32

    // zero tagged h buffers (tag0|h=0 valid initial) + counters
    hipMemsetAsync(ws, 0, WS_NEED, stream);

    gru_scan<<<NWG_TOT, 256, 0, stream>>>(x, Wi0, bi0, Wh0, bhn0,
                                          Wi1, bi1, Wh1, bhn1,
                                          c0, c1, y0u, y1u, ws);
    dense_out<<<64, 256, 0, stream>>>(c1, Wout, bout, out);
}

// Round 9
// 7321.516 us; speedup vs baseline: 1.5247x; 1.5247x over previous
//
#include <hip/hip_runtime.h>

// ---------------------------------------------------------------------------
// 2-layer GRU (B=64, T=1024, D=256, H=512) + dense head, persistent-RNN style.
// v10 = v9 with the asm fix: global_load_dwordx2 destination must be a 64-bit
// aligned VGPR pair -> single uint2 output operand (was two scalar "=&v"
// outputs, which cannot encode -> compile error).
// v9 change over verified v4: the 64-line flag-gather barrier is replaced by
// two per-layer arrive counters packed in one 8-byte word.
//   - arrive: vmcnt(0) drain + __syncthreads + tid0 atomicAdd(cnt_layer, 1)
//   - wait: all lanes load the SAME dwordx2 (one line, broadcast) at sc1 and
//     check cnt0 >= 32*s && cnt1 >= 32*s  == v4's "all 64 flags >= s".
// Everything else is bit-identical to the verified v4. Hang-proof watchdogs.
// ---------------------------------------------------------------------------

#define T_STEPS 1024
#define NWG_L0  32
#define NWG_TOT 64

typedef _Float16 f16x8 __attribute__((ext_vector_type(8)));
typedef float    f32x4 __attribute__((ext_vector_type(4)));

// ws layout (bytes) -- identical to verified baseline
#define H0_OFF   0
#define H1_OFF   131072
#define Y0_OFF   262144
#define CNT_OFF  393216      // one 8B word: [cnt_L0, cnt_L1]

#define BUD_BAR  (1ull << 22)   // ~1.7ms @2.4GHz watchdog budget per barrier

#define WAITV0()   asm volatile("s_waitcnt vmcnt(0)")
#define SB()       __builtin_amdgcn_sched_barrier(0)
#define FENCE_VM() asm volatile("s_waitcnt vmcnt(0)" ::: "memory")

__device__ __forceinline__ float sigm_f(float x) { return 1.0f / (1.0f + __expf(-x)); }
__device__ __forceinline__ float tanh_f(float x) { return 2.0f / (1.0f + __expf(-2.0f * x)) - 1.0f; }

__device__ __forceinline__ f32x4 mfma16(f16x8 a, f16x8 b, f32x4 c) {
    return __builtin_amdgcn_mfma_f32_16x16x32_f16(a, b, c, 0, 0, 0);
}

__device__ __forceinline__ f16x8 pack8(const float* __restrict__ src, int stride) {
    f16x8 r;
#pragma unroll
    for (int j = 0; j < 8; ++j) r[j] = (_Float16)src[j * stride];
    return r;
}

// sc1 (device-coherent) 16B fragment load, NOT waited -- counted by caller.
__device__ __forceinline__ f16x8 ld_frag_a(const _Float16* p) {
    f16x8 v;
    asm volatile("global_load_dwordx4 %0, %1, off sc1" : "=v"(v) : "v"(p));
    return v;
}

// sc1 f16 store (verified)
__device__ __forceinline__ void st_dev_f16(_Float16* p, float v) {
    unsigned short b = __builtin_bit_cast(unsigned short, (_Float16)v);
    __hip_atomic_store((unsigned short*)p, b, __ATOMIC_RELAXED, __HIP_MEMORY_SCOPE_AGENT);
}

// arrive: drain this wave's mem ops, wg-sync, bump own layer counter
__device__ __forceinline__ void bar_arrive_cnt(unsigned* cnt) {
    asm volatile("s_waitcnt vmcnt(0)" ::: "memory");
    __syncthreads();
    if (threadIdx.x == 0) atomicAdd(cnt, 1u);
}

// wait: wave0 polls the single [cnt0,cnt1] dwordx2 (broadcast line), watchdog'd
__device__ __forceinline__ void bar_wait_cnt(const unsigned* cbase, int tgt,
                                             int wave, volatile unsigned* s_alive) {
    if (wave == 0 && *s_alive) {
        unsigned long long t0 = clock64();
        for (;;) {
            uint2 v;   // 64-bit aligned VGPR pair (dwordx2 dest requirement)
            asm volatile("global_load_dwordx2 %0, %1, off sc1\n\t"
                         "s_waitcnt vmcnt(0)"
                         : "=v"(v) : "v"(cbase) : "memory");
            if ((int)v.x >= tgt && (int)v.y >= tgt) break;
            if (clock64() - t0 > BUD_BAR) { if ((threadIdx.x & 63) == 0) *s_alive = 0; break; }
        }
    }
    __syncthreads();
    asm volatile("" ::: "memory");
}

#define BFRAG(g, kt) __builtin_bit_cast(f16x8, ldsB[((g) * 16 + (kt)) * 64 + lane])

__global__ __launch_bounds__(256, 1) void gru_scan(
    const float* __restrict__ x,     // [64,1024,256]
    const float* __restrict__ Wi0,   // [256,1536]
    const float* __restrict__ bi0,   // [1536]
    const float* __restrict__ Wh0,   // [512,1536]
    const float* __restrict__ bhn0,  // [512]
    const float* __restrict__ Wi1,   // [512,1536]
    const float* __restrict__ bi1,   // [1536]
    const float* __restrict__ Wh1,   // [512,1536]
    const float* __restrict__ bhn1,  // [512]
    float* __restrict__ c0_out,      // [64,512]
    float* __restrict__ c1_out,      // [64,512]
    unsigned char* __restrict__ ws)
{
    __shared__ uint4 ldsB[48 * 64];  // 48 KB: W_h fragments, frag idx nt*16+kt
    __shared__ unsigned s_alive;

    const int tid  = threadIdx.x;
    const int wave = tid >> 6;
    const int lane = tid & 63;
    const int quad = lane >> 4;
    const int l16  = lane & 15;
    const int wg   = blockIdx.x;
    const bool isL1 = (wg >= NWG_L0);
    const int cslice = (isL1 ? (wg - NWG_L0) : wg) * 16;

    if (tid == 0) s_alive = 1u;

    _Float16* h0buf = (_Float16*)(ws + H0_OFF);
    _Float16* h1buf = (_Float16*)(ws + H1_OFF);
    _Float16* y0buf = (_Float16*)(ws + Y0_OFF);
    unsigned* cbase = (unsigned*)(ws + CNT_OFF);   // [cnt_L0, cnt_L1]
    unsigned* myCnt = cbase + (isL1 ? 1 : 0);

    const float* Wh = isL1 ? Wh1 : Wh0;
    const float* Wi = isL1 ? Wi1 : Wi0;

    // ---- stage W_h fragments into LDS ----
    // B-frag (16x16x32): lane holds B[k = kt*32 + quad*8 + j][n = l16]
    for (int f = wave * 12; f < wave * 12 + 12; ++f) {
        int nt = f >> 4, kt = f & 15;
        const float* src = Wh + (kt * 32 + quad * 8) * 1536 + nt * 512 + cslice + l16;
        ldsB[f * 64 + lane] = __builtin_bit_cast(uint4, pack8(src, 1536));
    }

    // ---- W_i fragments in registers ----
    f16x8 wif[48];
    if (!isL1) {
#pragma unroll
        for (int nt = 0; nt < 3; ++nt)
#pragma unroll
            for (int kt = 0; kt < 8; ++kt)
                wif[nt * 8 + kt] = pack8(Wi + (kt * 32 + quad * 8) * 1536 + nt * 512 + cslice + l16, 1536);
    } else {
#pragma unroll
        for (int nt = 0; nt < 3; ++nt)
#pragma unroll
            for (int kt = 0; kt < 16; ++kt)
                wif[nt * 16 + kt] = pack8(Wi + (kt * 32 + quad * 8) * 1536 + nt * 512 + cslice + l16, 1536);
    }

    const float* bi = isL1 ? bi1 : bi0;
    const float* bh = isL1 ? bhn1 : bhn0;
    const float bi_r = bi[cslice + l16];
    const float bi_z = bi[512 + cslice + l16];
    const float bi_n = bi[1024 + cslice + l16];
    const float bhn  = bh[cslice + l16];

    __syncthreads();

    float hstate[4] = {0.f, 0.f, 0.f, 0.f};
    const int rowA = wave * 16 + l16;
    const int rowC = wave * 16 + quad * 4;
    const int cu   = cslice + l16;
    const f32x4 z4 = {0.f, 0.f, 0.f, 0.f};

    for (int s = 0; s < T_STEPS + 1; ++s) {
        const int pr = s & 1;

        // --- prefetch x for this step (overlaps the barrier wait) ---
        f32x4 xr[16];
        if (!isL1 && s < T_STEPS) {
            const float* px = x + (size_t)rowA * 262144 + s * 256 + quad * 8;
#pragma unroll
            for (int kt = 0; kt < 8; ++kt) {
                xr[kt * 2]     = *(const f32x4*)(px + kt * 32);
                xr[kt * 2 + 1] = *(const f32x4*)(px + kt * 32 + 4);
            }
        }

        if (s > 0) bar_wait_cnt(cbase, 32 * s, wave, &s_alive);

        if (!isL1 && s < T_STEPS) {
            const _Float16* hR = h0buf + pr * 32768;
            _Float16* hW = h0buf + (pr ^ 1) * 32768;
            _Float16* yW = y0buf + (pr ^ 1) * 32768;

            // All waves at vmcnt-clean point; x loads certainly complete.
            FENCE_VM();

            // convert x -> f16 A-fragments BEFORE issuing asm loads, so any
            // compiler-inserted wait for xr cannot drain our counted loads
            f16x8 axf[8];
#pragma unroll
            for (int kt = 0; kt < 8; ++kt) {
                f32x4 x0 = xr[kt * 2], x1 = xr[kt * 2 + 1];
                f16x8 a;
                a[0] = (_Float16)x0[0]; a[1] = (_Float16)x0[1];
                a[2] = (_Float16)x0[2]; a[3] = (_Float16)x0[3];
                a[4] = (_Float16)x1[0]; a[5] = (_Float16)x1[1];
                a[6] = (_Float16)x1[2]; a[7] = (_Float16)x1[3];
                axf[kt] = a;
            }
            SB();

            // issue ALL 16 h-fragment loads up-front (pipelined in MALL)
            f16x8 hb[16];
#pragma unroll
            for (int p = 0; p < 16; ++p)
                hb[p] = ld_frag_a(hR + rowA * 512 + p * 32 + quad * 8);

            // x-side MFMAs overlap the load round-trip (register-only)
            f32x4 ax0 = z4, ax1 = z4, ax2 = z4;
#pragma unroll
            for (int kt = 0; kt < 8; ++kt) {
                ax0 = mfma16(axf[kt], wif[0 * 8 + kt], ax0);
                ax1 = mfma16(axf[kt], wif[1 * 8 + kt], ax1);
                ax2 = mfma16(axf[kt], wif[2 * 8 + kt], ax2);
            }

            SB(); WAITV0(); SB();   // all 16 h frags in regs (rule #18 fence)

            f32x4 ah0 = z4, ah1 = z4, ah2 = z4;
#pragma unroll
            for (int kt = 0; kt < 16; ++kt) {
                f16x8 a = hb[kt];
                ah0 = mfma16(a, BFRAG(0, kt), ah0);
                ah1 = mfma16(a, BFRAG(1, kt), ah1);
                ah2 = mfma16(a, BFRAG(2, kt), ah2);
            }

#pragma unroll
            for (int i = 0; i < 4; ++i) {
                const int b = rowC + i;
                float r = sigm_f(ax0[i] + bi_r + ah0[i]);
                float z = sigm_f(ax1[i] + bi_z + ah1[i]);
                float n = tanh_f(ax2[i] + bi_n + r * (ah2[i] + bhn));
                float hnew = (1.0f - z) * n + z * hstate[i];
                hstate[i] = hnew;
                st_dev_f16(&hW[b * 512 + cu], hnew);
                st_dev_f16(&yW[b * 512 + cu], tanh_f(hnew));
                if (s == T_STEPS - 1) c0_out[b * 512 + cu] = hnew;
            }
        }

        if (isL1 && s >= 1) {
            const _Float16* hR = h1buf + pr * 32768;
            _Float16* hW = h1buf + (pr ^ 1) * 32768;
            const _Float16* yR = y0buf + pr * 32768;  // y0 from global step s-1

            FENCE_VM();
            SB();

            // phase A: issue 8 (h,y) pairs up-front
            f16x8 hb[8], yb[8];
#pragma unroll
            for (int p = 0; p < 8; ++p) {
                hb[p] = ld_frag_a(hR + rowA * 512 + p * 32 + quad * 8);
                yb[p] = ld_frag_a(yR + rowA * 512 + p * 32 + quad * 8);
            }

            SB(); WAITV0(); SB();   // pairs 0..7 in regs

            f32x4 ah0 = z4, ah1 = z4, ah2 = z4, ax0 = z4, ax1 = z4, ax2 = z4;
#pragma unroll
            for (int kt = 0; kt < 8; ++kt) {
                f16x8 ah = hb[kt], ay = yb[kt];
                ah0 = mfma16(ah, BFRAG(0, kt), ah0);
                ah1 = mfma16(ah, BFRAG(1, kt), ah1);
                ah2 = mfma16(ah, BFRAG(2, kt), ah2);
                ax0 = mfma16(ay, wif[0 * 16 + kt], ax0);
                ax1 = mfma16(ay, wif[1 * 16 + kt], ax1);
                ax2 = mfma16(ay, wif[2 * 16 + kt], ax2);
                // refill slot kt with pair kt+8 (phase B), overlaps compute
                hb[kt] = ld_frag_a(hR + rowA * 512 + (kt + 8) * 32 + quad * 8);
                yb[kt] = ld_frag_a(yR + rowA * 512 + (kt + 8) * 32 + quad * 8);
            }

            SB(); WAITV0(); SB();   // pairs 8..15 in regs

#pragma unroll
            for (int kt = 8; kt < 16; ++kt) {
                f16x8 ah = hb[kt - 8], ay = yb[kt - 8];
                ah0 = mfma16(ah, BFRAG(0, kt), ah0);
                ah1 = mfma16(ah, BFRAG(1, kt), ah1);
                ah2 = mfma16(ah, BFRAG(2, kt), ah2);
                ax0 = mfma16(ay, wif[0 * 16 + kt], ax0);
                ax1 = mfma16(ay, wif[1 * 16 + kt], ax1);
                ax2 = mfma16(ay, wif[2 * 16 + kt], ax2);
            }

#pragma unroll
            for (int i = 0; i < 4; ++i) {
                const int b = rowC + i;
                float r = sigm_f(ax0[i] + bi_r + ah0[i]);
                float z = sigm_f(ax1[i] + bi_z + ah1[i]);
                float n = tanh_f(ax2[i] + bi_n + r * (ah2[i] + bhn));
                float hnew = (1.0f - z) * n + z * hstate[i];
                hstate[i] = hnew;
                st_dev_f16(&hW[b * 512 + cu], hnew);
                if (s == T_STEPS) c1_out[b * 512 + cu] = hnew;
            }
        }

        if (s < T_STEPS) bar_arrive_cnt(myCnt);
    }
}

// out = tanh(tanh(c1) @ W_out + b_out) : [64,512] @ [512,512], fp32
__global__ __launch_bounds__(256) void dense_out(
    const float* __restrict__ c1, const float* __restrict__ Wout,
    const float* __restrict__ bout, float* __restrict__ out)
{
    __shared__ float a[512];
    const int b = blockIdx.x, tid = threadIdx.x;
    a[tid]       = tanh_f(c1[b * 512 + tid]);
    a[tid + 256] = tanh_f(c1[b * 512 + tid + 256]);
    __syncthreads();
    float acc0 = 0.f, acc1 = 0.f;
#pragma unroll 4
    for (int k = 0; k < 512; ++k) {
        const float av = a[k];
        acc0 += av * Wout[k * 512 + tid];
        acc1 += av * Wout[k * 512 + tid + 256];
    }
    out[b * 512 + tid]       = tanh_f(acc0 + bout[tid]);
    out[b * 512 + tid + 256] = tanh_f(acc1 + bout[tid + 256]);
}

extern "C" void kernel_launch(void* const* d_in, const int* in_sizes, int n_in,
                              void* d_out, int out_size, void* d_ws, size_t ws_size,
                              hipStream_t stream)
{
    const float* x    = (const float*)d_in[0];
    const float* Wi0  = (const float*)d_in[1];
    const float* bi0  = (const float*)d_in[2];
    const float* Wh0  = (const float*)d_in[3];
    const float* bhn0 = (const float*)d_in[4];
    const float* Wi1  = (const float*)d_in[5];
    const float* bi1  = (const float*)d_in[6];
    const float* Wh1  = (const float*)d_in[7];
    const float* bhn1 = (const float*)d_in[8];
    const float* Wout = (const float*)d_in[9];
    const float* bout = (const float*)d_in[10];
    float* out = (float*)d_out;
    unsigned char* ws = (unsigned char*)d_ws;

    // zero h/y double buffers + counters (ws poisoned 0xAA each launch)
    (void)hipMemsetAsync(ws, 0, CNT_OFF + 128, stream);

    gru_scan<<<NWG_TOT, 256, 0, stream>>>(x, Wi0, bi0, Wh0, bhn0,
                                          Wi1, bi1, Wh1, bhn1,
                                          out + 32768, out + 65536, ws);
    dense_out<<<64, 256, 0, stream>>>(out + 65536, Wout, bout, out);
}